// Round 1
// baseline (268.858 us; speedup 1.0000x reference)
//
#include <hip/hip_runtime.h>

#define HH 512
#define WW 512
#define NPLANES 96        // 32 * 3
#define BLOCK 256
#define COLS_PB 256
#define ROWS_PB 128
#define COL_TILES 2       // 512 / 256
#define ROW_TILES 4       // 512 / 128
#define HALO 5
#define KW 11
#define LDSW (COLS_PB + 2 * HALO)   // 266
#define NFULL 11                    // 11 full groups of 11 rows = 121
#define NREM 7                      // + 7 remainder rows = 128

#define C1V 1e-4f                   // (0.01*1.0)^2
#define C2V 9e-4f                   // (0.03*1.0)^2
#define EPSV 1e-8f
#define NPIX 25165824.0f            // 32*3*512*512

struct Rings {
  float hx[KW], hy[KW], hx2[KW], hy2[KW], hxy[KW];
};

__device__ __forceinline__ void stage_rows(float (*sx)[LDSW], float (*sy)[LDSW],
                                           const float* __restrict__ xp,
                                           const float* __restrict__ yp,
                                           int C0, int firstRow, int nRows, int tid)
{
  for (int r = 0; r < nRows; ++r) {
    const int ri = firstRow + r;
    const bool rok = (ri >= 0) && (ri < HH);
    const float* xrow = xp + (ptrdiff_t)ri * WW;
    const float* yrow = yp + (ptrdiff_t)ri * WW;
    #pragma unroll
    for (int c0 = 0; c0 < LDSW; c0 += BLOCK) {
      const int c = c0 + tid;
      if (c < LDSW) {
        const int gc = C0 - HALO + c;
        const bool ok = rok && (gc >= 0) && (gc < WW);
        sx[r][c] = ok ? xrow[gc] : 0.f;
        sy[r][c] = ok ? yrow[gc] : 0.f;
      }
    }
  }
}

// horizontal 11-tap blur of x, y, x^2, y^2, xy at one (row, col)
__device__ __forceinline__ void hblur(const float* sxr, const float* syr,
                                      const float* wv, int tid,
                                      float& ohx, float& ohy, float& ohx2,
                                      float& ohy2, float& ohxy)
{
  float hx = 0.f, hy = 0.f, hx2 = 0.f, hy2 = 0.f, hxy = 0.f;
  #pragma unroll
  for (int k = 0; k < KW; ++k) {
    const float xv = sxr[tid + k];
    const float yv = syr[tid + k];
    const float t = wv[k] * xv;
    const float u = wv[k] * yv;
    hx += t;
    hy += u;
    hx2 = fmaf(t, xv, hx2);
    hy2 = fmaf(u, yv, hy2);
    hxy = fmaf(t, yv, hxy);
  }
  ohx = hx; ohy = hy; ohx2 = hx2; ohy2 = hy2; ohxy = hxy;
}

// prologue: fill ring slot J from LDS row J (no output produced)
template <int J>
__device__ __forceinline__ void pro_step(Rings& rg, float (*sx)[LDSW], float (*sy)[LDSW],
                                         const float* wv, int tid)
{
  hblur(sx[J], sy[J], wv, tid, rg.hx[J], rg.hy[J], rg.hx2[J], rg.hy2[J], rg.hxy[J]);
}

// steady state: new h-row from LDS row P into ring slot (P+10)%11,
// then vertical blur over slots (P+k)%11 and the SSIM epilogue.
// All ring indices are compile-time constants (rule #20).
template <int P>
__device__ __forceinline__ void phase_step(Rings& rg, float (*sx)[LDSW], float (*sy)[LDSW],
                                           const float* wv, int tid, float& acc)
{
  constexpr int SNEW = (P + 2 * HALO) % KW;
  hblur(sx[P], sy[P], wv, tid,
        rg.hx[SNEW], rg.hy[SNEW], rg.hx2[SNEW], rg.hy2[SNEW], rg.hxy[SNEW]);

  float mx = 0.f, my = 0.f, ex2 = 0.f, ey2 = 0.f, exy = 0.f;
  #pragma unroll
  for (int k = 0; k < KW; ++k) {
    const int s = (P + k) % KW;   // constant after unroll
    mx  = fmaf(wv[k], rg.hx[s],  mx);
    my  = fmaf(wv[k], rg.hy[s],  my);
    ex2 = fmaf(wv[k], rg.hx2[s], ex2);
    ey2 = fmaf(wv[k], rg.hy2[s], ey2);
    exy = fmaf(wv[k], rg.hxy[s], exy);
  }
  const float mx2 = mx * mx, my2 = my * my, mxy = mx * my;
  const float sx2 = ex2 - mx2, sy2 = ey2 - my2, sxy = exy - mxy;
  const float num = fmaf(2.f, mxy, C1V) * fmaf(2.f, sxy, C2V);
  const float den = (mx2 + my2 + C1V) * (sx2 + sy2 + C2V);
  acc += num * __builtin_amdgcn_rcpf(den + EPSV);
}

__global__ __launch_bounds__(BLOCK) void ssim_main(const float* __restrict__ x,
                                                   const float* __restrict__ y,
                                                   float* __restrict__ partial)
{
  __shared__ float sx[KW][LDSW];
  __shared__ float sy[KW][LDSW];
  __shared__ float wsum[BLOCK / 64];

  const int tid = threadIdx.x;
  const int plane = blockIdx.y;
  const int colT = blockIdx.x & (COL_TILES - 1);
  const int rowT = blockIdx.x / COL_TILES;
  const int C0 = colT * COLS_PB;
  const int R0 = rowT * ROWS_PB;

  const float* xp = x + (ptrdiff_t)plane * (HH * WW);
  const float* yp = y + (ptrdiff_t)plane * (HH * WW);

  // Gaussian window, exact reference formula (normalized 1D, fp32)
  float wv[KW];
  {
    float s = 0.f;
    #pragma unroll
    for (int k = 0; k < KW; ++k) {
      const float d = (float)(k - HALO);
      wv[k] = expf(-(d * d) / 4.5f);   // 2*sigma^2 = 4.5
      s += wv[k];
    }
    const float inv = 1.f / s;
    #pragma unroll
    for (int k = 0; k < KW; ++k) wv[k] *= inv;
  }

  Rings rg;
  float acc = 0.f;

  // prologue: rows R0-5 .. R0+4 -> ring slots 0..9
  stage_rows(sx, sy, xp, yp, C0, R0 - HALO, 2 * HALO, tid);
  __syncthreads();
  pro_step<0>(rg, sx, sy, wv, tid);
  pro_step<1>(rg, sx, sy, wv, tid);
  pro_step<2>(rg, sx, sy, wv, tid);
  pro_step<3>(rg, sx, sy, wv, tid);
  pro_step<4>(rg, sx, sy, wv, tid);
  pro_step<5>(rg, sx, sy, wv, tid);
  pro_step<6>(rg, sx, sy, wv, tid);
  pro_step<7>(rg, sx, sy, wv, tid);
  pro_step<8>(rg, sx, sy, wv, tid);
  pro_step<9>(rg, sx, sy, wv, tid);

  const int riMain = R0 + HALO;   // first new input row of the main loop
  for (int g = 0; g < NFULL; ++g) {
    __syncthreads();                                        // prev group done reading LDS
    stage_rows(sx, sy, xp, yp, C0, riMain + g * KW, KW, tid);
    __syncthreads();
    phase_step<0>(rg, sx, sy, wv, tid, acc);
    phase_step<1>(rg, sx, sy, wv, tid, acc);
    phase_step<2>(rg, sx, sy, wv, tid, acc);
    phase_step<3>(rg, sx, sy, wv, tid, acc);
    phase_step<4>(rg, sx, sy, wv, tid, acc);
    phase_step<5>(rg, sx, sy, wv, tid, acc);
    phase_step<6>(rg, sx, sy, wv, tid, acc);
    phase_step<7>(rg, sx, sy, wv, tid, acc);
    phase_step<8>(rg, sx, sy, wv, tid, acc);
    phase_step<9>(rg, sx, sy, wv, tid, acc);
    phase_step<10>(rg, sx, sy, wv, tid, acc);
  }
  // remainder group: 7 more output rows
  __syncthreads();
  stage_rows(sx, sy, xp, yp, C0, riMain + NFULL * KW, NREM, tid);
  __syncthreads();
  phase_step<0>(rg, sx, sy, wv, tid, acc);
  phase_step<1>(rg, sx, sy, wv, tid, acc);
  phase_step<2>(rg, sx, sy, wv, tid, acc);
  phase_step<3>(rg, sx, sy, wv, tid, acc);
  phase_step<4>(rg, sx, sy, wv, tid, acc);
  phase_step<5>(rg, sx, sy, wv, tid, acc);
  phase_step<6>(rg, sx, sy, wv, tid, acc);

  // block reduction -> one atomic per block
  #pragma unroll
  for (int off = 32; off > 0; off >>= 1) acc += __shfl_down(acc, off);
  const int lane = tid & 63, wid = tid >> 6;
  if (lane == 0) wsum[wid] = acc;
  __syncthreads();
  if (tid == 0) atomicAdd(partial, wsum[0] + wsum[1] + wsum[2] + wsum[3]);
}

__global__ void zero_ws_kernel(float* __restrict__ ws) { ws[0] = 0.f; }

__global__ void finalize_kernel(const float* __restrict__ ws, float* __restrict__ out)
{
  out[0] = 1.f - ws[0] * (1.f / NPIX);
}

extern "C" void kernel_launch(void* const* d_in, const int* in_sizes, int n_in,
                              void* d_out, int out_size, void* d_ws, size_t ws_size,
                              hipStream_t stream)
{
  const float* x = (const float*)d_in[0];
  const float* y = (const float*)d_in[1];
  float* ws = (float*)d_ws;
  float* out = (float*)d_out;

  hipLaunchKernelGGL(zero_ws_kernel, dim3(1), dim3(1), 0, stream, ws);
  dim3 grid(COL_TILES * ROW_TILES, NPLANES);
  hipLaunchKernelGGL(ssim_main, grid, dim3(BLOCK), 0, stream, x, y, ws);
  hipLaunchKernelGGL(finalize_kernel, dim3(1), dim3(1), 0, stream, ws, out);
}

// Round 2
// 213.222 us; speedup vs baseline: 1.2609x; 1.2609x over previous
//
#include <hip/hip_runtime.h>

typedef float v2f __attribute__((ext_vector_type(2)));

#define HH 512
#define WW 512
#define NPLANES 96        // 32 * 3
#define BLOCK 64          // 1 wave per block
#define COLS_PB 128       // 64 threads x 2 columns
#define ROWS_PB 64
#define COL_TILES 4       // 512 / 128
#define ROW_TILES 8       // 512 / 64
#define HALO 5
#define KW 11
#define LDSW (COLS_PB + 2 * HALO)   // 138
#define NFULL 5                     // 5 full groups of 11 rows = 55
#define NREM 9                      // + 9 remainder rows = 64

#define C1V 1e-4f                   // (0.01*1.0)^2
#define C2V 9e-4f                   // (0.03*1.0)^2
#define EPSV 1e-8f
#define NPIX 25165824.0f            // 32*3*512*512

// per-thread ring buffers: horizontal-blur results for 11 rows x 2 columns
struct Rings {
  v2f hx[KW], hy[KW], hx2[KW], hy2[KW], hxy[KW];
};

__device__ __forceinline__ void stage_rows(float (*sx)[LDSW], float (*sy)[LDSW],
                                           const float* __restrict__ xp,
                                           const float* __restrict__ yp,
                                           int C0, int firstRow, int nRows, int tid)
{
  for (int r = 0; r < nRows; ++r) {
    const int ri = firstRow + r;
    const bool rok = (ri >= 0) && (ri < HH);
    const float* xrow = xp + (ptrdiff_t)ri * WW;
    const float* yrow = yp + (ptrdiff_t)ri * WW;
    #pragma unroll
    for (int c0 = 0; c0 < LDSW; c0 += BLOCK) {
      const int c = c0 + tid;
      if (c < LDSW) {
        const int gc = C0 - HALO + c;
        const bool ok = rok && (gc >= 0) && (gc < WW);
        sx[r][c] = ok ? xrow[gc] : 0.f;
        sy[r][c] = ok ? yrow[gc] : 0.f;
      }
    }
  }
}

// horizontal 11-tap blur for a 2-column pair; taps are 12 contiguous floats
// loaded as 6 x ds_read_b64 per array. All math packed fp32 (v_pk_*).
__device__ __forceinline__ void hblur(const float* sxr, const float* syr,
                                      const float* wv, int tid,
                                      v2f& ohx, v2f& ohy, v2f& ohx2,
                                      v2f& ohy2, v2f& ohxy)
{
  const v2f* xr = (const v2f*)sxr;   // rows are 8B-aligned (138 floats = 552 B)
  const v2f* yr = (const v2f*)syr;
  v2f X[6], Y[6];
  #pragma unroll
  for (int j = 0; j < 6; ++j) { X[j] = xr[tid + j]; Y[j] = yr[tid + j]; }

  v2f hx = {0.f, 0.f}, hy = {0.f, 0.f};
  v2f hx2 = {0.f, 0.f}, hy2 = {0.f, 0.f}, hxy = {0.f, 0.f};
  #pragma unroll
  for (int k = 0; k < KW; ++k) {
    const int j = k >> 1;
    v2f xp, yp;
    if ((k & 1) == 0) { xp = X[j]; yp = Y[j]; }
    else {
      xp.x = X[j].y; xp.y = X[j + 1].x;
      yp.x = Y[j].y; yp.y = Y[j + 1].x;
    }
    const float w = wv[k];
    const v2f t = w * xp;
    const v2f u = w * yp;
    hx += t;
    hy += u;
    hx2 = __builtin_elementwise_fma(t, xp, hx2);
    hy2 = __builtin_elementwise_fma(u, yp, hy2);
    hxy = __builtin_elementwise_fma(t, yp, hxy);
  }
  ohx = hx; ohy = hy; ohx2 = hx2; ohy2 = hy2; ohxy = hxy;
}

template <int J>
__device__ __forceinline__ void pro_step(Rings& rg, float (*sx)[LDSW], float (*sy)[LDSW],
                                         const float* wv, int tid)
{
  hblur(sx[J], sy[J], wv, tid, rg.hx[J], rg.hy[J], rg.hx2[J], rg.hy2[J], rg.hxy[J]);
}

// new h-row from LDS row P -> ring slot (P+10)%11, then vertical blur + SSIM.
// All ring indices compile-time (rule #20: no runtime-indexed reg arrays).
template <int P>
__device__ __forceinline__ void phase_step(Rings& rg, float (*sx)[LDSW], float (*sy)[LDSW],
                                           const float* wv, int tid, v2f& acc)
{
  constexpr int SNEW = (P + 2 * HALO) % KW;
  hblur(sx[P], sy[P], wv, tid,
        rg.hx[SNEW], rg.hy[SNEW], rg.hx2[SNEW], rg.hy2[SNEW], rg.hxy[SNEW]);

  v2f mx = {0.f, 0.f}, my = {0.f, 0.f};
  v2f ex2 = {0.f, 0.f}, ey2 = {0.f, 0.f}, exy = {0.f, 0.f};
  #pragma unroll
  for (int k = 0; k < KW; ++k) {
    const int s = (P + k) % KW;   // constant after unroll
    const float w = wv[k];
    mx  = __builtin_elementwise_fma((v2f)(w), rg.hx[s],  mx);
    my  = __builtin_elementwise_fma((v2f)(w), rg.hy[s],  my);
    ex2 = __builtin_elementwise_fma((v2f)(w), rg.hx2[s], ex2);
    ey2 = __builtin_elementwise_fma((v2f)(w), rg.hy2[s], ey2);
    exy = __builtin_elementwise_fma((v2f)(w), rg.hxy[s], exy);
  }
  const v2f mx2 = mx * mx, my2 = my * my, mxy = mx * my;
  const v2f sx2 = ex2 - mx2, sy2 = ey2 - my2, sxy = exy - mxy;
  const v2f num = (2.f * mxy + C1V) * (2.f * sxy + C2V);
  const v2f den = (mx2 + my2 + C1V) * (sx2 + sy2 + C2V) + EPSV;
  v2f r;
  r.x = __builtin_amdgcn_rcpf(den.x);
  r.y = __builtin_amdgcn_rcpf(den.y);
  acc = __builtin_elementwise_fma(num, r, acc);
}

__global__ __launch_bounds__(BLOCK) void ssim_main(const float* __restrict__ x,
                                                   const float* __restrict__ y,
                                                   float* __restrict__ partial)
{
  __shared__ float sx[KW][LDSW];
  __shared__ float sy[KW][LDSW];

  const int tid = threadIdx.x;
  const int plane = blockIdx.y;
  const int colT = blockIdx.x & (COL_TILES - 1);
  const int rowT = blockIdx.x / COL_TILES;
  const int C0 = colT * COLS_PB;
  const int R0 = rowT * ROWS_PB;

  const float* xp = x + (ptrdiff_t)plane * (HH * WW);
  const float* yp = y + (ptrdiff_t)plane * (HH * WW);

  // Gaussian window (exact reference formula), then force into SGPRs:
  // all lanes compute identical values -> readfirstlane is safe and frees VGPRs.
  float wv[KW];
  {
    float s = 0.f;
    #pragma unroll
    for (int k = 0; k < KW; ++k) {
      const float d = (float)(k - HALO);
      wv[k] = expf(-(d * d) / 4.5f);   // 2*sigma^2 = 4.5
      s += wv[k];
    }
    const float inv = 1.f / s;
    #pragma unroll
    for (int k = 0; k < KW; ++k) {
      wv[k] *= inv;
      wv[k] = __int_as_float(__builtin_amdgcn_readfirstlane(__float_as_int(wv[k])));
    }
  }

  Rings rg;
  v2f acc = {0.f, 0.f};

  // prologue: rows R0-5 .. R0+4 -> ring slots 0..9
  stage_rows(sx, sy, xp, yp, C0, R0 - HALO, 2 * HALO, tid);
  __syncthreads();
  pro_step<0>(rg, sx, sy, wv, tid);
  pro_step<1>(rg, sx, sy, wv, tid);
  pro_step<2>(rg, sx, sy, wv, tid);
  pro_step<3>(rg, sx, sy, wv, tid);
  pro_step<4>(rg, sx, sy, wv, tid);
  pro_step<5>(rg, sx, sy, wv, tid);
  pro_step<6>(rg, sx, sy, wv, tid);
  pro_step<7>(rg, sx, sy, wv, tid);
  pro_step<8>(rg, sx, sy, wv, tid);
  pro_step<9>(rg, sx, sy, wv, tid);

  const int riMain = R0 + HALO;
  for (int g = 0; g < NFULL; ++g) {
    __syncthreads();
    stage_rows(sx, sy, xp, yp, C0, riMain + g * KW, KW, tid);
    __syncthreads();
    phase_step<0>(rg, sx, sy, wv, tid, acc);
    phase_step<1>(rg, sx, sy, wv, tid, acc);
    phase_step<2>(rg, sx, sy, wv, tid, acc);
    phase_step<3>(rg, sx, sy, wv, tid, acc);
    phase_step<4>(rg, sx, sy, wv, tid, acc);
    phase_step<5>(rg, sx, sy, wv, tid, acc);
    phase_step<6>(rg, sx, sy, wv, tid, acc);
    phase_step<7>(rg, sx, sy, wv, tid, acc);
    phase_step<8>(rg, sx, sy, wv, tid, acc);
    phase_step<9>(rg, sx, sy, wv, tid, acc);
    phase_step<10>(rg, sx, sy, wv, tid, acc);
  }
  // remainder: 9 more output rows
  __syncthreads();
  stage_rows(sx, sy, xp, yp, C0, riMain + NFULL * KW, NREM, tid);
  __syncthreads();
  phase_step<0>(rg, sx, sy, wv, tid, acc);
  phase_step<1>(rg, sx, sy, wv, tid, acc);
  phase_step<2>(rg, sx, sy, wv, tid, acc);
  phase_step<3>(rg, sx, sy, wv, tid, acc);
  phase_step<4>(rg, sx, sy, wv, tid, acc);
  phase_step<5>(rg, sx, sy, wv, tid, acc);
  phase_step<6>(rg, sx, sy, wv, tid, acc);
  phase_step<7>(rg, sx, sy, wv, tid, acc);
  phase_step<8>(rg, sx, sy, wv, tid, acc);

  // single-wave block: shuffle reduce, one atomic per block
  float a = acc.x + acc.y;
  #pragma unroll
  for (int off = 32; off > 0; off >>= 1) a += __shfl_down(a, off);
  if (tid == 0) atomicAdd(partial, a);
}

__global__ void zero_ws_kernel(float* __restrict__ ws) { ws[0] = 0.f; }

__global__ void finalize_kernel(const float* __restrict__ ws, float* __restrict__ out)
{
  out[0] = 1.f - ws[0] * (1.f / NPIX);
}

extern "C" void kernel_launch(void* const* d_in, const int* in_sizes, int n_in,
                              void* d_out, int out_size, void* d_ws, size_t ws_size,
                              hipStream_t stream)
{
  const float* x = (const float*)d_in[0];
  const float* y = (const float*)d_in[1];
  float* ws = (float*)d_ws;
  float* out = (float*)d_out;

  hipLaunchKernelGGL(zero_ws_kernel, dim3(1), dim3(1), 0, stream, ws);
  dim3 grid(COL_TILES * ROW_TILES, NPLANES);
  hipLaunchKernelGGL(ssim_main, grid, dim3(BLOCK), 0, stream, x, y, ws);
  hipLaunchKernelGGL(finalize_kernel, dim3(1), dim3(1), 0, stream, ws, out);
}